// Round 1
// 622.972 us; speedup vs baseline: 1.0967x; 1.0967x over previous
//
#include <hip/hip_runtime.h>
#include <hip/hip_bf16.h>
#include <stdint.h>

typedef unsigned short u16;
typedef __bf16 bf16x8 __attribute__((ext_vector_type(8)));
typedef float floatx4 __attribute__((ext_vector_type(4)));

__device__ __forceinline__ u16 f2bf(float f) {
  union { float f; unsigned u; } c; c.f = f;
  unsigned r = c.u + 0x7fffu + ((c.u >> 16) & 1u);
  return (u16)(r >> 16);
}

__device__ __forceinline__ void load_lds16(const void* g, void* l) {
  __builtin_amdgcn_global_load_lds(
      (const __attribute__((address_space(1))) void*)g,
      (__attribute__((address_space(3))) void*)l,
      16, 0, 0);
}

__device__ __forceinline__ void memclob() { asm volatile("" ::: "memory"); }
__device__ __forceinline__ void barrier_() {
  memclob();
  __builtin_amdgcn_s_barrier();
  memclob();
}

// ---- preamble: cast x -> bf16 | transpose W0 | transpose W1 | zero z ----
// one launch, block ranges; saved ~40us vs separate dispatches (R4 data).
__global__ __launch_bounds__(256) void preamble(
    const float* __restrict__ x, const float* __restrict__ W0,
    const float* __restrict__ W1,
    u16* __restrict__ Xb, u16* __restrict__ Wt0, u16* __restrict__ Wt1,
    float* __restrict__ z)
{
  __shared__ float tile[32][33];
  const int bid = blockIdx.x;
  const int t = threadIdx.x;

  if (bid < 32768) {                      // cast x: 32768*1024 floats, float4/thread
    int i = bid * 256 + t;
    float4 f = ((const float4*)x)[i];
    ushort4 u;
    u.x = f2bf(f.x); u.y = f2bf(f.y); u.z = f2bf(f.z); u.w = f2bf(f.w);
    ((ushort4*)Xb)[i] = u;
  } else if (bid < 32768 + 2048) {        // transpose W0 [1024,2048] -> [2048,1024]
    int tb = bid - 32768;
    int bx = (tb & 63) * 32, by = (tb >> 6) * 32;
    int tx = t & 31, ty = t >> 5;
    #pragma unroll
    for (int i = 0; i < 32; i += 8)
      tile[ty + i][tx] = W0[(size_t)(by + ty + i) * 2048 + bx + tx];
    __syncthreads();
    #pragma unroll
    for (int i = 0; i < 32; i += 8)
      Wt0[(size_t)(bx + ty + i) * 1024 + by + tx] = f2bf(tile[tx][ty + i]);
  } else if (bid < 32768 + 2048 + 4096) { // transpose W1 [2048,2048]
    int tb = bid - (32768 + 2048);
    int bx = (tb & 63) * 32, by = (tb >> 6) * 32;
    int tx = t & 31, ty = t >> 5;
    #pragma unroll
    for (int i = 0; i < 32; i += 8)
      tile[ty + i][tx] = W1[(size_t)(by + ty + i) * 2048 + bx + tx];
    __syncthreads();
    #pragma unroll
    for (int i = 0; i < 32; i += 8)
      Wt1[(size_t)(bx + ty + i) * 2048 + by + tx] = f2bf(tile[tx][ty + i]);
  } else {                                // zero z[32768]: 32 blocks x 256 x float4
    int tb = bid - (32768 + 2048 + 4096);
    ((float4*)z)[tb * 256 + t] = (float4){0.f, 0.f, 0.f, 0.f};
  }
}

// ============ 256x256 8-phase GEMM: elu(A[M,K] @ Bt[N,K]^T + bias) ============
// T2+T3+T4+T5 schedule (guide §5 256² template, adapted to our verified swizzle):
//   - 8 waves (2M x 4N), per-wave C = 128x64, acc[8][4] 16x16x32 bf16 MFMA.
//   - LDS 128 KB = 2 parity x {A-lo, A-hi, B-lo, B-hi} slots of 16 KB.
//     A-lo = tile rows with (r>>6)&1==0 (i0-3 rows of both wm halves), slot-row
//     sr = (r&63) + ((r>>7)<<6).  B-lo = (r>>5)&1==0 (j0-1 rows of all wn),
//     sr = (r&31) + ((r>>6)<<5).  In every case sr&7 == lm&7 on the read side,
//     so the proven chunk-XOR swizzle (stored chunk = logical ^ (sr&7)) gives
//     0 bank conflicts, and global_load_lds stays linear (source pre-swizzled).
//   - 4 phases per K-tile g (parity p=g&1):
//       P0: ds_read A-lo+B-lo | stage B1(g+1)->lds[p^1] | bar | 16 MFMA | bar
//       P1: ds_read A-hi      | stage A0(g+2)->lds[p]   | bar | 16 MFMA | bar
//       P2: ds_read B-hi      | stage A1(g+2)->lds[p]   | bar | 16 MFMA | bar
//       P3:                   | stage B0(g+2), vmcnt(6) | bar | 16 MFMA | bar
//     Every stage targets a slot whose last ds_read finished >=1 barrier ago
//     (WAR-safe).  vmcnt(6) = 3 half-tiles (A0,A1,B0 of g+2) stay in flight
//     across barriers — never drained to 0 in the main loop (T4).
//   - raw s_barrier (NOT __syncthreads — that forces a vmcnt(0) drain, the
//     documented ~20% stall of the old 128² structure).
//   - setprio(1) around each MFMA cluster (T5; pays only with this phase split).
//   - XCD-chunked bijective block swizzle (grid=1024, %8==0): 8 consecutive
//     blocks share one A-stripe inside one XCD's L2.
// FUSE_HEAD: per-row partial dot with W2 (fp32), butterfly-reduce over the
// 16-lane col group, atomicAdd into z[M] (h1 never stored).
template<bool FUSE_HEAD>
__global__ __launch_bounds__(512, 2) void gemm256_8p(
    const u16* __restrict__ A,      // [M, K] bf16
    const u16* __restrict__ Bt,     // [N, K] bf16
    const float* __restrict__ bias, // [N]
    u16* __restrict__ C,            // [M, N] bf16 (unused if FUSE_HEAD)
    const float* __restrict__ W2,   // [N] (used if FUSE_HEAD)
    float* __restrict__ z,          // [M] fp32 accum (used if FUSE_HEAD)
    int M, int N, int K)
{
  __shared__ u16 lds[65536];  // 128 KB; 8 slots x 8192 u16

  const int t = threadIdx.x;
  const int l = t & 63;
  const int w = t >> 6;
  const int wm = w >> 2;       // 0..1
  const int wn = w & 3;        // 0..3
  const int lm = l & 15;
  const int q  = l >> 4;       // 0..3

  // XCD-chunked swizzle; grid is (M/256)*(N/256) = 1024, divisible by 8.
  const int nwg = gridDim.x;
  int wg = blockIdx.x;
  wg = (wg & 7) * (nwg >> 3) + (wg >> 3);
  const int nbn = N >> 8;
  const int n0 = (wg % nbn) << 8;
  const int m0 = (wg / nbn) << 8;

  // ---- staging geometry: per half-tile 2 instrs x 512 thr x 16B = 16 KB.
  // instr n, thread t -> slot-row sr = n*64 + (t>>3), stored chunk t&7,
  // logical chunk (t&7)^((t>>3)&7)  (sr&7 == (t>>3)&7 always). ----
  const int rowoff = t >> 3;                     // 0..63
  const int lc8 = ((t & 7) ^ (rowoff & 7)) * 8;  // logical chunk, u16 units
  const u16* ApA0 = A + (size_t)(m0 + rowoff) * K + lc8;        // n=0: rows s*64+rowoff
  const u16* ApA1 = A + (size_t)(m0 + 128 + rowoff) * K + lc8;  // n=1: +128
  const int bq = rowoff >> 5;                    // B instr-n row group
  const int br = rowoff & 31;
  const u16* BpB0 = Bt + (size_t)(n0 + bq * 64 + br) * K + lc8;        // wn' = bq
  const u16* BpB1 = Bt + (size_t)(n0 + (2 + bq) * 64 + br) * K + lc8;  // wn' = 2+bq
  const int ldst = t * 8;                        // u16 dest offset; +4096 for n=1

#define SLOT(p, idx) (((p) * 4 + (idx)) * 8192)  // idx: 0=A-lo 1=A-hi 2=B-lo 3=B-hi

  auto stage_a = [&](int p, int s, int kt) {
    load_lds16(ApA0 + (size_t)s * 64 * K + (size_t)kt * 64, &lds[SLOT(p, s) + ldst]);
    load_lds16(ApA1 + (size_t)s * 64 * K + (size_t)kt * 64, &lds[SLOT(p, s) + 4096 + ldst]);
  };
  auto stage_b = [&](int p, int s, int kt) {
    load_lds16(BpB0 + (size_t)s * 32 * K + (size_t)kt * 64, &lds[SLOT(p, 2 + s) + ldst]);
    load_lds16(BpB1 + (size_t)s * 32 * K + (size_t)kt * 64, &lds[SLOT(p, 2 + s) + 4096 + ldst]);
  };

  // ---- read geometry ----
  const int ck0 = ((0 * 4 + q) ^ (lm & 7)) * 8;  // kk=0 swizzled chunk
  const int ck1 = ((1 * 4 + q) ^ (lm & 7)) * 8;  // kk=1
  const int arow = (wm * 64 + lm) * 64;          // + (i&3)*1024
  const int brow = (wn * 32 + lm) * 64;          // + (j&1)*1024
#define RDA(p, i, ck) (*(const bf16x8*)&lds[SLOT(p, (i) >> 2) + arow + ((i) & 3) * 1024 + (ck)])
#define RDB(p, j, ck) (*(const bf16x8*)&lds[SLOT(p, 2 + ((j) >> 1)) + brow + ((j) & 1) * 1024 + (ck)])
#define MFMA(d, x, y) d = __builtin_amdgcn_mfma_f32_16x16x32_bf16(x, y, d, 0, 0, 0)

  floatx4 acc[8][4];
  #pragma unroll
  for (int i = 0; i < 8; ++i)
    #pragma unroll
    for (int j = 0; j < 4; ++j)
      acc[i][j] = (floatx4){0.f, 0.f, 0.f, 0.f};

  bf16x8 a[8][2];   // a-lo live P0-P2, a-hi live P1-P3
  bf16x8 b[2][2];   // b-lo P0-P1, overwritten by b-hi at P2

  const int NK = K >> 6;

  // ---- prologue: K-tile 0 (4 half-tiles) + K-tile 1 (A0,A1,B0). memclob
  // between stages pins issue order so the vmcnt horizon is exact. ----
  stage_a(0, 0, 0); memclob(); stage_a(0, 1, 0); memclob();
  stage_b(0, 0, 0); memclob(); stage_b(0, 1, 0); memclob();
  stage_a(1, 0, 1); memclob(); stage_a(1, 1, 1); memclob();
  stage_b(1, 0, 1);
  asm volatile("s_waitcnt vmcnt(6)" ::: "memory");  // K-tile 0 landed; 3 in flight
  barrier_();

  #pragma unroll 2
  for (int g = 0; g < NK; ++g) {
    const int p = g & 1;
    const bool s1 = (g + 1 < NK);
    const bool s2 = (g + 2 < NK);

    // ---------- P0: read A-lo + B-lo; stage B1(g+1) ----------
    #pragma unroll
    for (int i = 0; i < 4; ++i) { a[i][0] = RDA(p, i, ck0); a[i][1] = RDA(p, i, ck1); }
    #pragma unroll
    for (int j = 0; j < 2; ++j) { b[j][0] = RDB(p, j, ck0); b[j][1] = RDB(p, j, ck1); }
    if (s1) stage_b(p ^ 1, 1, g + 1);
    barrier_();
    __builtin_amdgcn_s_setprio(1);
    #pragma unroll
    for (int i = 0; i < 4; ++i)
      #pragma unroll
      for (int j = 0; j < 2; ++j) {
        MFMA(acc[i][j], a[i][0], b[j][0]);
        MFMA(acc[i][j], a[i][1], b[j][1]);
      }
    __builtin_amdgcn_s_setprio(0);
    barrier_();

    // ---------- P1: read A-hi; stage A0(g+2) ----------
    #pragma unroll
    for (int i = 4; i < 8; ++i) { a[i][0] = RDA(p, i, ck0); a[i][1] = RDA(p, i, ck1); }
    if (s2) stage_a(p, 0, g + 2);
    barrier_();
    __builtin_amdgcn_s_setprio(1);
    #pragma unroll
    for (int i = 4; i < 8; ++i)
      #pragma unroll
      for (int j = 0; j < 2; ++j) {
        MFMA(acc[i][j], a[i][0], b[j][0]);
        MFMA(acc[i][j], a[i][1], b[j][1]);
      }
    __builtin_amdgcn_s_setprio(0);
    barrier_();

    // ---------- P2: read B-hi (reuse b regs); stage A1(g+2) ----------
    #pragma unroll
    for (int j = 0; j < 2; ++j) { b[j][0] = RDB(p, 2 + j, ck0); b[j][1] = RDB(p, 2 + j, ck1); }
    if (s2) stage_a(p, 1, g + 2);
    barrier_();
    __builtin_amdgcn_s_setprio(1);
    #pragma unroll
    for (int i = 0; i < 4; ++i)
      #pragma unroll
      for (int j = 0; j < 2; ++j) {
        MFMA(acc[i][2 + j], a[i][0], b[j][0]);
        MFMA(acc[i][2 + j], a[i][1], b[j][1]);
      }
    __builtin_amdgcn_s_setprio(0);
    barrier_();

    // ---------- P3: stage B0(g+2); counted vmcnt (never 0 mid-loop) ----------
    if (s2) {
      stage_b(p, 0, g + 2);
      asm volatile("s_waitcnt vmcnt(6)" ::: "memory");  // retires through B1(g+1)
    } else if (s1) {
      asm volatile("s_waitcnt vmcnt(0)" ::: "memory");  // tail: drain B1(NK-1)
    }
    barrier_();
    __builtin_amdgcn_s_setprio(1);
    #pragma unroll
    for (int i = 4; i < 8; ++i)
      #pragma unroll
      for (int j = 0; j < 2; ++j) {
        MFMA(acc[i][2 + j], a[i][0], b[j][0]);
        MFMA(acc[i][2 + j], a[i][1], b[j][1]);
      }
    __builtin_amdgcn_s_setprio(0);
    barrier_();
  }

  // ---------------------------- epilogue ----------------------------
  float bv[4];
  #pragma unroll
  for (int j = 0; j < 4; ++j) bv[j] = bias[n0 + wn * 64 + j * 16 + lm];

  if (!FUSE_HEAD) {
    #pragma unroll
    for (int i = 0; i < 8; ++i) {
      #pragma unroll
      for (int r = 0; r < 4; ++r) {
        int grow = m0 + wm * 128 + i * 16 + q * 4 + r;
        size_t base = (size_t)grow * N + n0 + wn * 64 + lm;
        #pragma unroll
        for (int j = 0; j < 4; ++j) {
          float v = acc[i][j][r] + bv[j];
          v = v > 0.f ? v : (__expf(v) - 1.f);
          C[base + j * 16] = f2bf(v);
        }
      }
    }
  } else {
    float w2v[4];
    #pragma unroll
    for (int j = 0; j < 4; ++j) w2v[j] = W2[n0 + wn * 64 + j * 16 + lm];
    #pragma unroll
    for (int i = 0; i < 8; ++i) {
      #pragma unroll
      for (int r = 0; r < 4; ++r) {
        float pacc = 0.f;
        #pragma unroll
        for (int j = 0; j < 4; ++j) {
          float v = acc[i][j][r] + bv[j];
          v = v > 0.f ? v : (__expf(v) - 1.f);
          pacc += v * w2v[j];
        }
        pacc += __shfl_xor(pacc, 1);
        pacc += __shfl_xor(pacc, 2);
        pacc += __shfl_xor(pacc, 4);
        pacc += __shfl_xor(pacc, 8);
        if (lm == 0) atomicAdd(&z[m0 + wm * 128 + i * 16 + q * 4 + r], pacc);
      }
    }
  }
#undef SLOT
#undef RDA
#undef RDB
#undef MFMA
}

// ------------- finish: out = sigmoid(z + b2); alpha = acti(out) -------------
__global__ __launch_bounds__(256) void sigmoid_alpha(
    const float* __restrict__ z, const float* __restrict__ b2,
    float* __restrict__ out, int B)
{
  int i = blockIdx.x * blockDim.x + threadIdx.x;
  if (i >= B) return;
  float o = 1.f / (1.f + expf(-(z[i] + b2[0])));
  float alpha;
  if (o <= 0.2f)      alpha = 0.1f - 0.5f * o;
  else if (o >= 0.8f) alpha = 0.5f * o - 0.4f;
  else                alpha = 0.f;
  out[i] = o;
  out[B + i] = alpha;
}

extern "C" void kernel_launch(void* const* d_in, const int* in_sizes, int n_in,
                              void* d_out, int out_size, void* d_ws, size_t ws_size,
                              hipStream_t stream) {
  const int BATCH = 32768, IN = 1024, HID = 2048;

  const float* x  = (const float*)d_in[0];
  const float* W0 = (const float*)d_in[1];
  const float* b0 = (const float*)d_in[2];
  const float* W1 = (const float*)d_in[3];
  const float* b1 = (const float*)d_in[4];
  const float* W2 = (const float*)d_in[5];
  const float* b2 = (const float*)d_in[6];
  float* out = (float*)d_out;

  char* ws = (char*)d_ws;
  u16* Xb   = (u16*)(ws);                       // 64 MB [32768,1024]
  u16* Wt0  = (u16*)(ws + (size_t)67108864);    // 4 MB  [2048,1024]
  u16* Wt1  = (u16*)(ws + (size_t)71303168);    // 8 MB  [2048,2048]
  u16* h0   = (u16*)(ws + (size_t)79691776);    // 128 MB [32768,2048]
  float* z  = (float*)(ws + (size_t)213909504); // 128 KB [32768]

  const int grid = (BATCH / 256) * (HID / 256); // 1024, divisible by 8

  // 1) preamble: cast x, transpose W0/W1, zero z
  preamble<<<32768 + 2048 + 4096 + 32, 256, 0, stream>>>(x, W0, W1, Xb, Wt0, Wt1, z);
  // 2) h0 = elu(Xb @ Wt0^T + b0)
  gemm256_8p<false><<<grid, 512, 0, stream>>>(
      Xb, Wt0, b0, h0, nullptr, nullptr, BATCH, HID, IN);
  // 3) z += rows of elu(h0 @ Wt1^T + b1) dotted with W2 (h1 never stored)
  gemm256_8p<true><<<grid, 512, 0, stream>>>(
      h0, Wt1, b1, nullptr, W2, z, BATCH, HID, HID);
  // 4) out + alpha
  sigmoid_alpha<<<BATCH / 256, 256, 0, stream>>>(z, b2, out, BATCH);
}